// Round 7
// baseline (1700.514 us; speedup 1.0000x reference)
//
#include <hip/hip_runtime.h>
#include <math.h>
#include <stdint.h>

typedef int v4i  __attribute__((ext_vector_type(4)));
typedef int v16i __attribute__((ext_vector_type(16)));

#define NTOK 8192
#define HID  4096
#define FFND 14336

typedef const __attribute__((address_space(1))) void* gp_t;
typedef __attribute__((address_space(3))) void*       lp_t;

#define BAR()      __builtin_amdgcn_s_barrier()
#define SETPRIO(p) __builtin_amdgcn_s_setprio(p)
#define MEMFENCE() asm volatile("" ::: "memory")

// ------------- pack int32 weights (values in [-127,127]) -> int8 -------------
__global__ __launch_bounds__(256) void k_pack_w(
    const int* __restrict__ w32, int8_t* __restrict__ w8, int n4) {
  int i = blockIdx.x * 256 + threadIdx.x;
  if (i >= n4) return;
  int4 v = reinterpret_cast<const int4*>(w32)[i];
  reinterpret_cast<int*>(w8)[i] =
      (v.x & 255) | ((v.y & 255) << 8) | ((v.z & 255) << 16) | ((v.w & 255) << 24);
}

// ---------------- quantize x: fp32 -> int8, 4 elems/thread ----------------
__global__ __launch_bounds__(256) void k_quant_x(
    const float* __restrict__ x, int8_t* __restrict__ q,
    const float* __restrict__ sp, int n4) {
  int i = blockIdx.x * 256 + threadIdx.x;
  if (i >= n4) return;
  float s = *sp;
  float4 v = reinterpret_cast<const float4*>(x)[i];
  int a = (int)rintf(v.x / s); a = a < -128 ? -128 : (a > 127 ? 127 : a);
  int b = (int)rintf(v.y / s); b = b < -128 ? -128 : (b > 127 ? 127 : b);
  int c = (int)rintf(v.z / s); c = c < -128 ? -128 : (c > 127 ? 127 : c);
  int d = (int)rintf(v.w / s); d = d < -128 ? -128 : (d > 127 ? 127 : d);
  reinterpret_cast<int*>(q)[i] =
      (a & 255) | ((b & 255) << 8) | ((c & 255) << 16) | ((d & 255) << 24);
}

// ---- stage one [ROWS][64 bytes] int8 tile into LDS (XOR-swizzled) ----
// LDS physical: row*64 + slot*16; stored(row,slot) = global(row, slot^((row>>1)&3)).
// global_load_lds dest is linear (wave-uniform base + lane*16); swizzle applied on
// the per-lane SOURCE address and inverted identically on the read side (rule #21).
template <int ROWS, int NWAVES>
__device__ __forceinline__ void stage_tile(const int8_t* __restrict__ src,
                                           int ld, int8_t* lds,
                                           int wave, int lane) {
  constexpr int NSEG = ROWS / 16;          // 1 KiB segments
  constexpr int PER  = NSEG / NWAVES;
#pragma unroll
  for (int j = 0; j < PER; ++j) {
    const int seg  = wave * PER + j;
    const int o    = (seg << 10) + (lane << 4);
    const int row  = o >> 6;
    const int slot = (o >> 4) & 3;
    const int gs   = slot ^ ((row >> 1) & 3);
    const int8_t* g = src + (size_t)row * ld + (gs << 4);
    __builtin_amdgcn_global_load_lds((gp_t)g, (lp_t)(lds + (seg << 10)), 16, 0, 0);
  }
}

// read one 16B MFMA fragment (row, linear k-slot) with the inverse swizzle
__device__ __forceinline__ v4i frag16(const int8_t* lds, int row, int sl) {
  const int s2 = sl ^ ((row >> 1) & 3);
  return *reinterpret_cast<const v4i*>(lds + (row << 6) + (s2 << 4));
}

// ------- GEMM1: q1[T,H] x {w1,w3}[FFN,H]^T -> SwiGLU -> q2 int8 -------
// 512 thr / 8 waves; tile 256x128 dual; depth-3 LDS (96 KiB, 1 block/CU).
// Cross-phase register pipeline: read(kk1) || MFMA(kk0); read(next,kk0) || MFMA(kk1).
// One barrier + one combined waitcnt per K-tile; vmcnt(4) counted, never 0 in steady state.
__global__ __launch_bounds__(512, 2) void k_gemm1(
    const int8_t* __restrict__ q1, const int8_t* __restrict__ w1,
    const int8_t* __restrict__ w3, int8_t* __restrict__ q2,
    const float* __restrict__ w1sp, const float* __restrict__ w3sp,
    const float* __restrict__ a1sp, const float* __restrict__ a2sp) {
  __shared__ __align__(16) int8_t As[3][256 * 64];   // 48 KiB
  __shared__ __align__(16) int8_t B1s[3][128 * 64];  // 24 KiB
  __shared__ __align__(16) int8_t B3s[3][128 * 64];  // 24 KiB
  const int lane = threadIdx.x & 63;
  const int wave = threadIdx.x >> 6;   // 0..7
  const int wr = wave >> 1;            // 0..3  (M quadrant, 64 rows)
  const int wc = wave & 1;             // 0..1  (N half, 64 cols)
  const int r0 = lane & 31;
  const int sl0 = (lane >> 5);         // kk0 slot
  const int sl1 = 2 + (lane >> 5);     // kk1 slot
  const int mbase = blockIdx.y * 256;
  const int nbase = blockIdx.x * 128;
  const int8_t* Ap  = q1 + (size_t)mbase * HID;
  const int8_t* B1p = w1 + (size_t)nbase * HID;
  const int8_t* B3p = w3 + (size_t)nbase * HID;
  constexpr int NT = HID / 64;

  v16i acc1[2][2], acc3[2][2];
#pragma unroll
  for (int m = 0; m < 2; ++m)
#pragma unroll
    for (int n = 0; n < 2; ++n)
#pragma unroll
      for (int r = 0; r < 16; ++r) { acc1[m][n][r] = 0; acc3[m][n][r] = 0; }

  // prologue: issue K-tiles 0,1 (4 loads/wave/tile, FIFO); wait tile 0; read P0.
#pragma unroll
  for (int t = 0; t < 2; ++t) {
    stage_tile<256, 8>(Ap  + t * 64, HID, As[t],  wave, lane);
    stage_tile<128, 8>(B1p + t * 64, HID, B1s[t], wave, lane);
    stage_tile<128, 8>(B3p + t * 64, HID, B3s[t], wave, lane);
  }
  asm volatile("s_waitcnt vmcnt(4)" ::: "memory");
  BAR(); MEMFENCE();

  v4i p0a[2], p0b1[2], p0b3[2], p1a[2], p1b1[2], p1b3[2];
  p0a[0]  = frag16(As[0],  wr * 64 +      r0, sl0);
  p0a[1]  = frag16(As[0],  wr * 64 + 32 + r0, sl0);
  p0b1[0] = frag16(B1s[0], wc * 64 +      r0, sl0);
  p0b1[1] = frag16(B1s[0], wc * 64 + 32 + r0, sl0);
  p0b3[0] = frag16(B3s[0], wc * 64 +      r0, sl0);
  p0b3[1] = frag16(B3s[0], wc * 64 + 32 + r0, sl0);

  int cur = 0;
  for (int kt = 0; kt < NT; ++kt) {
    const int nx1 = (cur == 2) ? 0 : cur + 1;        // (kt+1)%3
    const int nx2 = (cur >= 1) ? cur - 1 : 2;        // (kt+2)%3
    const int8_t* Ac  = As[cur];
    const int8_t* B1c = B1s[cur];
    const int8_t* B3c = B3s[cur];
    // step 1: read P1 <- (kt, kk1)
    p1a[0]  = frag16(Ac,  wr * 64 +      r0, sl1);
    p1a[1]  = frag16(Ac,  wr * 64 + 32 + r0, sl1);
    p1b1[0] = frag16(B1c, wc * 64 +      r0, sl1);
    p1b1[1] = frag16(B1c, wc * 64 + 32 + r0, sl1);
    p1b3[0] = frag16(B3c, wc * 64 +      r0, sl1);
    p1b3[1] = frag16(B3c, wc * 64 + 32 + r0, sl1);
    // step 2: MFMA(P0) overlaps step-1 reads
    SETPRIO(1);
#pragma unroll
    for (int m = 0; m < 2; ++m)
#pragma unroll
      for (int n = 0; n < 2; ++n) {
        acc1[m][n] = __builtin_amdgcn_mfma_i32_32x32x32_i8(p0a[m], p0b1[n], acc1[m][n], 0, 0, 0);
        acc3[m][n] = __builtin_amdgcn_mfma_i32_32x32x32_i8(p0a[m], p0b3[n], acc3[m][n], 0, 0, 0);
      }
    SETPRIO(0);
    // step 3: stage kt+2 (buf last read at kt-1; all waves' reads drained pre-barrier)
    if (kt + 2 < NT) {
      stage_tile<256, 8>(Ap  + (kt + 2) * 64, HID, As[nx2],  wave, lane);
      stage_tile<128, 8>(B1p + (kt + 2) * 64, HID, B1s[nx2], wave, lane);
      stage_tile<128, 8>(B3p + (kt + 2) * 64, HID, B3s[nx2], wave, lane);
      asm volatile("s_waitcnt vmcnt(4) lgkmcnt(0)" ::: "memory");
    } else {
      asm volatile("s_waitcnt vmcnt(0) lgkmcnt(0)" ::: "memory");
    }
    // step 4: barrier — tile kt+1 in LDS; every wave's outstanding reads drained
    BAR(); MEMFENCE();
    // step 5: read P0 <- (kt+1, kk0)
    if (kt + 1 < NT) {
      const int8_t* An  = As[nx1];
      const int8_t* B1n = B1s[nx1];
      const int8_t* B3n = B3s[nx1];
      p0a[0]  = frag16(An,  wr * 64 +      r0, sl0);
      p0a[1]  = frag16(An,  wr * 64 + 32 + r0, sl0);
      p0b1[0] = frag16(B1n, wc * 64 +      r0, sl0);
      p0b1[1] = frag16(B1n, wc * 64 + 32 + r0, sl0);
      p0b3[0] = frag16(B3n, wc * 64 +      r0, sl0);
      p0b3[1] = frag16(B3n, wc * 64 + 32 + r0, sl0);
    }
    // step 6: MFMA(P1) overlaps step-5 reads
    SETPRIO(1);
#pragma unroll
    for (int m = 0; m < 2; ++m)
#pragma unroll
      for (int n = 0; n < 2; ++n) {
        acc1[m][n] = __builtin_amdgcn_mfma_i32_32x32x32_i8(p1a[m], p1b1[n], acc1[m][n], 0, 0, 0);
        acc3[m][n] = __builtin_amdgcn_mfma_i32_32x32x32_i8(p1a[m], p1b3[n], acc3[m][n], 0, 0, 0);
      }
    SETPRIO(0);
    cur = nx1;
  }

  const float s1 = (*a1sp) * (*w1sp);
  const float s3 = (*a1sp) * (*w3sp);
  const float ia2 = 1.f / (*a2sp);
#pragma unroll
  for (int m = 0; m < 2; ++m)
#pragma unroll
    for (int n = 0; n < 2; ++n) {
      const int colg = nbase + wc * 64 + n * 32 + r0;
#pragma unroll
      for (int r = 0; r < 16; ++r) {
        const int rowg = mbase + wr * 64 + m * 32 +
                         (r & 3) + ((r >> 2) << 3) + ((lane >> 5) << 2);
        const float g = (float)acc1[m][n][r] * s1;
        const float u = (float)acc3[m][n][r] * s3;
        const float h = g * __builtin_amdgcn_rcpf(1.f + __expf(-g)) * u;
        float t = rintf(h * ia2);
        t = fminf(fmaxf(t, -128.f), 127.f);
        q2[(size_t)rowg * FFND + colg] = (int8_t)(int)t;
      }
    }
}

// ------- GEMM2: q2[T,FFN] x w2[HID,FFN]^T -> fp32 out -------
// 256 thr / 4 waves; tile 128(M)x256(N); per-wave 64x128 (12 reads : 16 MFMA);
// depth-3 (72 KiB -> 2 blocks/CU); same pipelined schedule; vmcnt(6).
__global__ __launch_bounds__(256, 2) void k_gemm2(
    const int8_t* __restrict__ q2, const int8_t* __restrict__ w2,
    float* __restrict__ out,
    const float* __restrict__ w2sp, const float* __restrict__ a2sp) {
  __shared__ __align__(16) int8_t As[3][128 * 64];  // 24 KiB
  __shared__ __align__(16) int8_t Bs[3][256 * 64];  // 48 KiB
  const int lane = threadIdx.x & 63;
  const int wave = threadIdx.x >> 6;   // 0..3
  const int wr = wave >> 1;            // 0..1  (M half, 64 rows)
  const int wch = wave & 1;            // 0..1  (N half, 128 cols)
  const int r0 = lane & 31;
  const int sl0 = (lane >> 5);
  const int sl1 = 2 + (lane >> 5);
  const int mbase = blockIdx.y * 128;
  const int nbase = blockIdx.x * 256;
  const int8_t* Ap = q2 + (size_t)mbase * FFND;
  const int8_t* Bp = w2 + (size_t)nbase * FFND;
  constexpr int NT = FFND / 64;

  v16i acc[2][4];
#pragma unroll
  for (int m = 0; m < 2; ++m)
#pragma unroll
    for (int n = 0; n < 4; ++n)
#pragma unroll
      for (int r = 0; r < 16; ++r) acc[m][n][r] = 0;

  // prologue (6 loads/wave/tile: A 2 + B 4)
#pragma unroll
  for (int t = 0; t < 2; ++t) {
    stage_tile<128, 4>(Ap + t * 64, FFND, As[t], wave, lane);
    stage_tile<256, 4>(Bp + t * 64, FFND, Bs[t], wave, lane);
  }
  asm volatile("s_waitcnt vmcnt(6)" ::: "memory");
  BAR(); MEMFENCE();

  v4i p0a[2], p0b[4], p1a[2], p1b[4];
  p0a[0] = frag16(As[0], wr * 64 +      r0, sl0);
  p0a[1] = frag16(As[0], wr * 64 + 32 + r0, sl0);
#pragma unroll
  for (int n = 0; n < 4; ++n)
    p0b[n] = frag16(Bs[0], wch * 128 + n * 32 + r0, sl0);

  int cur = 0;
  for (int kt = 0; kt < NT; ++kt) {
    const int nx1 = (cur == 2) ? 0 : cur + 1;
    const int nx2 = (cur >= 1) ? cur - 1 : 2;
    const int8_t* Ac = As[cur];
    const int8_t* Bc = Bs[cur];
    // read P1 <- (kt, kk1)
    p1a[0] = frag16(Ac, wr * 64 +      r0, sl1);
    p1a[1] = frag16(Ac, wr * 64 + 32 + r0, sl1);
#pragma unroll
    for (int n = 0; n < 4; ++n)
      p1b[n] = frag16(Bc, wch * 128 + n * 32 + r0, sl1);
    // MFMA(P0)
    SETPRIO(1);
#pragma unroll
    for (int m = 0; m < 2; ++m)
#pragma unroll
      for (int n = 0; n < 4; ++n)
        acc[m][n] = __builtin_amdgcn_mfma_i32_32x32x32_i8(p0a[m], p0b[n], acc[m][n], 0, 0, 0);
    SETPRIO(0);
    // stage kt+2
    if (kt + 2 < NT) {
      stage_tile<128, 4>(Ap + (kt + 2) * 64, FFND, As[nx2], wave, lane);
      stage_tile<256, 4>(Bp + (kt + 2) * 64, FFND, Bs[nx2], wave, lane);
      asm volatile("s_waitcnt vmcnt(6) lgkmcnt(0)" ::: "memory");
    } else {
      asm volatile("s_waitcnt vmcnt(0) lgkmcnt(0)" ::: "memory");
    }
    BAR(); MEMFENCE();
    // read P0 <- (kt+1, kk0)
    if (kt + 1 < NT) {
      const int8_t* An = As[nx1];
      const int8_t* Bn = Bs[nx1];
      p0a[0] = frag16(An, wr * 64 +      r0, sl0);
      p0a[1] = frag16(An, wr * 64 + 32 + r0, sl0);
#pragma unroll
      for (int n = 0; n < 4; ++n)
        p0b[n] = frag16(Bn, wch * 128 + n * 32 + r0, sl0);
    }
    // MFMA(P1)
    SETPRIO(1);
#pragma unroll
    for (int m = 0; m < 2; ++m)
#pragma unroll
      for (int n = 0; n < 4; ++n)
        acc[m][n] = __builtin_amdgcn_mfma_i32_32x32x32_i8(p1a[m], p1b[n], acc[m][n], 0, 0, 0);
    SETPRIO(0);
    cur = nx1;
  }

  const float s = (*a2sp) * (*w2sp);
#pragma unroll
  for (int m = 0; m < 2; ++m)
#pragma unroll
    for (int n = 0; n < 4; ++n) {
      const int colg = nbase + wch * 128 + n * 32 + r0;
#pragma unroll
      for (int r = 0; r < 16; ++r) {
        const int rowg = mbase + wr * 64 + m * 32 +
                         (r & 3) + ((r >> 2) << 3) + ((lane >> 5) << 2);
        out[(size_t)rowg * HID + colg] = (float)acc[m][n][r] * s;
      }
    }
}

extern "C" void kernel_launch(void* const* d_in, const int* in_sizes, int n_in,
                              void* d_out, int out_size, void* d_ws, size_t ws_size,
                              hipStream_t stream) {
  const float* x    = (const float*)d_in[0];
  const int*   w1i  = (const int*)d_in[1];   // int8 values stored as int32
  const int*   w3i  = (const int*)d_in[2];
  const int*   w2i  = (const int*)d_in[3];
  const float* w1s  = (const float*)d_in[4];
  const float* w3s  = (const float*)d_in[5];
  const float* w2s  = (const float*)d_in[6];
  const float* a1s  = (const float*)d_in[7];
  const float* a2s  = (const float*)d_in[8];
  float* out = (float*)d_out;

  // workspace layout
  int8_t* q1  = (int8_t*)d_ws;                         // [NTOK][HID]    33.5 MB
  int8_t* q2  = q1 + (size_t)NTOK * HID;               // [NTOK][FFND]  117.4 MB
  int8_t* w1p = q2 + (size_t)NTOK * FFND;              // [FFN][HID]     58.7 MB
  int8_t* w3p = w1p + (size_t)FFND * HID;              //                58.7 MB
  int8_t* w2p = w3p + (size_t)FFND * HID;              // [HID][FFN]     58.7 MB

  const int wn4 = (int)((size_t)FFND * HID / 4);
  k_pack_w<<<wn4 / 256, 256, 0, stream>>>(w1i, w1p, wn4);
  k_pack_w<<<wn4 / 256, 256, 0, stream>>>(w3i, w3p, wn4);
  k_pack_w<<<wn4 / 256, 256, 0, stream>>>(w2i, w2p, wn4);

  const int n4 = NTOK * HID / 4;
  k_quant_x<<<n4 / 256, 256, 0, stream>>>(x, q1, a1s, n4);
  k_gemm1<<<dim3(FFND / 128, NTOK / 256), 512, 0, stream>>>(
      q1, w1p, w3p, q2, w1s, w3s, a1s, a2s);
  k_gemm2<<<dim3(HID / 256, NTOK / 128), 256, 0, stream>>>(
      q2, w2p, out, w2s, a2s);
}